// Round 6
// baseline (98.537 us; speedup 1.0000x reference)
//
#include <hip/hip_runtime.h>

// SimpleMatcher: B=128, N=900 preds, T=300 targets.
// out = [pred_idx (B*T), valid (B*T), max_iou (B*T)] as float.
//
// R6: latency-bound diagnosis -> 5 targets per lane (300 = 60 lanes x 5):
//  - 1 LDS pred broadcast amortized over 320 pairs (LDS pipe /5)
//  - 5 independent dep chains per lane -> ILP hides ds_read/rcp latency
//  - block = (b, ns) covers ALL 300 targets; NSPLIT=9 -> grid 1152
// Numerics unchanged: g = (inter*ea + uni*(uni-ea)) * rcp(uni*ea), abs err
// <= ~5e-7; MARGIN 2e-5 -> approx argmax provably exact when best-second >
// MARGIN; winner recomputed bit-exactly; ambiguous targets exhaustively
// rescanned with IEEE math + numpy first-occurrence tie-break.

#define BB 128
#define NN 900
#define TT 300
#define NSPLIT 9       // n-splits across blocks
#define NPB 100        // preds per block  (NN / NSPLIT)
#define NPW 25         // preds per wave   (NPB / 4)
#define TPL 5          // targets per lane
#define ALANES 60      // active lanes per wave (60*5 = 300)
#define MARGIN 2e-5f

// Bit-exact GIoU in numpy's exact expression order.
__device__ __forceinline__ float giou_exact(float4 pb, float4 tb) {
#pragma clang fp contract(off)
    float px0 = pb.x - 0.5f * pb.z, py0 = pb.y - 0.5f * pb.w;
    float px1 = pb.x + 0.5f * pb.z, py1 = pb.y + 0.5f * pb.w;
    float tx0 = tb.x - 0.5f * tb.z, ty0 = tb.y - 0.5f * tb.w;
    float tx1 = tb.x + 0.5f * tb.z, ty1 = tb.y + 0.5f * tb.w;
    float pa = (px1 - px0) * (py1 - py0);
    float ta = (tx1 - tx0) * (ty1 - ty0);
    float w  = fmaxf(fminf(px1, tx1) - fmaxf(px0, tx0), 0.f);
    float h  = fmaxf(fminf(py1, ty1) - fmaxf(py0, ty0), 0.f);
    float inter = w * h;
    float uni   = pa + ta - inter;
    float iou   = inter / uni;            // correctly-rounded IEEE div
    float ew = fmaxf(fmaxf(px1, tx1) - fminf(px0, tx0), 0.f);
    float eh = fmaxf(fmaxf(py1, ty1) - fminf(py0, ty0), 0.f);
    float ea = ew * eh;
    return iou - (ea - uni) / ea;         // correctly-rounded IEEE div
}

__global__ __launch_bounds__(256, 6) void matcher_scan_kernel(
    const float* __restrict__ pred,       // [B,N,4] cxcywh
    const float* __restrict__ tgt,        // [B,T,4] cxcywh
    float* __restrict__ pbest,            // [NSPLIT][B*T]
    float* __restrict__ psec,             // [NSPLIT][B*T]
    int*   __restrict__ pidx)             // [NSPLIT][B*T]
{
    __shared__ float4 sp[NPB];            // pred xyxy
    __shared__ float  spa[NPB];           // pred area
    __shared__ float  sbv[4 * TT], ssv[4 * TT];
    __shared__ int    siv[4 * TT];

    const int ns  = blockIdx.x % NSPLIT;
    const int b   = blockIdx.x / NSPLIT;
    const int tid = threadIdx.x;
    const int l   = tid & 63;
    const int ng  = tid >> 6;

    if (tid < NPB) {
        const float4 pb = ((const float4*)pred)[b * NN + ns * NPB + tid];
        float4 q;
        q.x = pb.x - 0.5f * pb.z;
        q.y = pb.y - 0.5f * pb.w;
        q.z = pb.x + 0.5f * pb.z;
        q.w = pb.y + 0.5f * pb.w;
        sp[tid]  = q;
        spa[tid] = (q.z - q.x) * (q.w - q.y);
    }

    // ---- 5 target boxes per lane (lanes 0..59 active) ----
    float tx0[TPL], ty0[TPL], tx1[TPL], ty1[TPL], ta[TPL];
    #pragma unroll
    for (int j = 0; j < TPL; ++j) {
        tx0[j] = ty0[j] = tx1[j] = ty1[j] = ta[j] = 0.f;
        if (l < ALANES) {
            const float4 tb = ((const float4*)tgt)[b * TT + j * ALANES + l];
            tx0[j] = tb.x - 0.5f * tb.z;
            ty0[j] = tb.y - 0.5f * tb.w;
            tx1[j] = tb.x + 0.5f * tb.z;
            ty1[j] = tb.y + 0.5f * tb.w;
            ta[j]  = (tx1[j] - tx0[j]) * (ty1[j] - ty0[j]);
        }
    }
    __syncthreads();

    float best[TPL], sec[TPL];
    int   bl[TPL];
    #pragma unroll
    for (int j = 0; j < TPL; ++j) { best[j] = -INFINITY; sec[j] = -INFINITY; bl[j] = 0; }

    const int k0 = ng * NPW;
    for (int k = 0; k < NPW; ++k) {
        const float4 p = sp[k0 + k];      // wave-uniform -> LDS broadcast
        const float pa = spa[k0 + k];
        #pragma unroll
        for (int j = 0; j < TPL; ++j) {
            const float w   = fmaxf(fminf(p.z, tx1[j]) - fmaxf(p.x, tx0[j]), 0.f);
            const float h   = fmaxf(fminf(p.w, ty1[j]) - fmaxf(p.y, ty0[j]), 0.f);
            const float inter = w * h;
            const float uni   = pa + ta[j] - inter;
            const float ew  = fmaxf(p.z, tx1[j]) - fminf(p.x, tx0[j]);  // >= 0
            const float eh  = fmaxf(p.w, ty1[j]) - fminf(p.y, ty0[j]);  // >= 0
            const float ea  = ew * eh;
            const float den = uni * ea;
            // g = inter/uni - (ea-uni)/ea = (inter*ea + uni*(uni-ea))/den
            const float num = fmaf(inter, ea, fmaf(uni, uni, -den));
            const float g   = num * __builtin_amdgcn_rcpf(den);

            sec[j] = __builtin_amdgcn_fmed3f(g, best[j], sec[j]);  // new 2nd
            if (g > best[j]) bl[j] = k;
            best[j] = fmaxf(best[j], g);
        }
    }

    if (l < ALANES) {
        #pragma unroll
        for (int j = 0; j < TPL; ++j) {
            const int u = j * ALANES + l;
            sbv[ng * TT + u] = best[j];
            ssv[ng * TT + u] = sec[j];
            siv[ng * TT + u] = k0 + bl[j];   // block-local pred index
        }
    }
    __syncthreads();

    // ---- distributed cross-wave reduce (ascending wave = ascending n) ----
    for (int u = tid; u < TT; u += 256) {
        float bb = -INFINITY, ss = -INFINITY;
        int   bi = 0;
        #pragma unroll
        for (int s = 0; s < 4; ++s) {
            const float ob = sbv[s * TT + u];
            const float os = ssv[s * TT + u];
            const int   oi = siv[s * TT + u];
            ss = fmaxf(fminf(bb, ob), fmaxf(ss, os));
            if (ob > bb) { bb = ob; bi = oi; }
        }
        const int bt = b * TT + u;
        pbest[ns * BB * TT + bt] = bb;
        psec [ns * BB * TT + bt] = ss;
        pidx [ns * BB * TT + bt] = ns * NPB + bi;   // global pred index
    }
}

__global__ __launch_bounds__(256) void matcher_finish_kernel(
    const float* __restrict__ pbest,
    const float* __restrict__ psec,
    const int*   __restrict__ pidx,
    const float* __restrict__ pred,
    const float* __restrict__ tgt,
    const unsigned char* __restrict__ mask,
    float* __restrict__ out)
{
    __shared__ int sflag[256];
    __shared__ int scount;

    const int tid = threadIdx.x;
    const int bt  = blockIdx.x * 256 + tid;   // grid covers exactly B*T
    if (tid == 0) scount = 0;
    __syncthreads();

    float best = -INFINITY, second = -INFINITY;
    int   bidx = 0;
    #pragma unroll
    for (int s = 0; s < NSPLIT; ++s) {        // ascending ns = ascending n
        const float ob = pbest[s * BB * TT + bt];
        const float os = psec [s * BB * TT + bt];
        const int   oi = pidx [s * BB * TT + bt];
        second = fmaxf(fminf(best, ob), fmaxf(second, os));
        if (ob > best) { best = ob; bidx = oi; }
    }

    if (best - second > MARGIN) {
        // approx argmax provably exact; recompute winner's GIoU bit-exactly
        const int b = bt / TT;
        const float4 pb = ((const float4*)pred)[b * NN + bidx];
        const float4 tb = ((const float4*)tgt)[bt];
        const float g = giou_exact(pb, tb);
        const bool valid = (mask[bt] != 0) && (g >= 0.5f);
        out[bt]               = (float)bidx;
        out[BB * TT + bt]     = valid ? 1.f : 0.f;
        out[2 * BB * TT + bt] = g;
    } else {
        const int pos = atomicAdd(&scount, 1);
        sflag[pos] = tid;
    }
    __syncthreads();

    // cooperative exact rescan of ambiguous targets: one wave per entry
    const int cnt  = scount;
    const int lane = tid & 63;
    const int ng   = tid >> 6;
    for (int f = ng; f < cnt; f += 4) {
        const int fbt = blockIdx.x * 256 + sflag[f];
        const int b   = fbt / TT;
        const float4 tb = ((const float4*)tgt)[fbt];

        float bestx = -INFINITY;
        int   bix   = NN;
        for (int n = lane; n < NN; n += 64) {   // ascending n per lane
            const float4 pb = ((const float4*)pred)[b * NN + n];
            const float g = giou_exact(pb, tb);
            if (g > bestx) { bestx = g; bix = n; }
        }
        // cross-lane reduce: max g, lowest n on bit-ties (numpy first-occ.)
        for (int off = 32; off >= 1; off >>= 1) {
            const float ob = __shfl_xor(bestx, off);
            const int   oi = __shfl_xor(bix, off);
            if (ob > bestx || (ob == bestx && oi < bix)) { bestx = ob; bix = oi; }
        }
        if (lane == 0) {
            const bool valid = (mask[fbt] != 0) && (bestx >= 0.5f);
            out[fbt]               = (float)bix;
            out[BB * TT + fbt]     = valid ? 1.f : 0.f;
            out[2 * BB * TT + fbt] = bestx;
        }
    }
}

extern "C" void kernel_launch(void* const* d_in, const int* in_sizes, int n_in,
                              void* d_out, int out_size, void* d_ws, size_t ws_size,
                              hipStream_t stream) {
    const float* pred = (const float*)d_in[0];
    const float* tgt  = (const float*)d_in[1];
    const unsigned char* mask = (const unsigned char*)d_in[2];
    float* out = (float*)d_out;

    const size_t seg = (size_t)NSPLIT * BB * TT * 4;   // 1.38 MB per array
    char* ws = (char*)d_ws;
    float* pbest = (float*)ws;
    float* psec  = (float*)(ws + seg);
    int*   pidx  = (int*)  (ws + 2 * seg);             // total ~4.15 MB

    matcher_scan_kernel<<<dim3(BB * NSPLIT), dim3(256), 0, stream>>>(
        pred, tgt, pbest, psec, pidx);
    matcher_finish_kernel<<<dim3(BB * TT / 256), dim3(256), 0, stream>>>(
        pbest, psec, pidx, pred, tgt, mask, out);
}

// Round 7
// 96.487 us; speedup vs baseline: 1.0212x; 1.0212x over previous
//
#include <hip/hip_runtime.h>

// SimpleMatcher: B=128, N=900 preds, T=300 targets.
// out = [pred_idx (B*T), valid (B*T), max_iou (B*T)] as float.
//
// R7 = R6 structure with the register budget FIXED:
//   R6 declared __launch_bounds__(256,6) -> 80-VGPR cap -> scratch spills
//   in the TPL=5 inner loop (the regression). Now (256,4) -> 128 VGPRs,
//   4 blocks/CU, 16 waves/CU; ~60-90 live regs fit without spilling.
//  - 5 targets per lane (60 lanes x 5 = 300): 1 LDS pred broadcast per
//    k serves 300 pairs; 5 independent dep chains hide VALU/LDS latency.
//  - NSPLIT=9 (NPB=100, NPW=25, exact), grid 1152.
// Numerics unchanged: g = (inter*ea + uni*(uni-ea)) * rcp(uni*ea), abs err
// <= ~5e-7; MARGIN 2e-5 -> approx argmax provably exact when best-second >
// MARGIN; winner recomputed bit-exactly; ambiguous targets exhaustively
// rescanned with IEEE math + numpy first-occurrence tie-break.

#define BB 128
#define NN 900
#define TT 300
#define NSPLIT 9       // n-splits across blocks
#define NPB 100        // preds per block  (NN / NSPLIT)
#define NPW 25         // preds per wave   (NPB / 4)
#define TPL 5          // targets per lane
#define ALANES 60      // active lanes per wave (60*5 = 300)
#define MARGIN 2e-5f

// Bit-exact GIoU in numpy's exact expression order.
__device__ __forceinline__ float giou_exact(float4 pb, float4 tb) {
#pragma clang fp contract(off)
    float px0 = pb.x - 0.5f * pb.z, py0 = pb.y - 0.5f * pb.w;
    float px1 = pb.x + 0.5f * pb.z, py1 = pb.y + 0.5f * pb.w;
    float tx0 = tb.x - 0.5f * tb.z, ty0 = tb.y - 0.5f * tb.w;
    float tx1 = tb.x + 0.5f * tb.z, ty1 = tb.y + 0.5f * tb.w;
    float pa = (px1 - px0) * (py1 - py0);
    float ta = (tx1 - tx0) * (ty1 - ty0);
    float w  = fmaxf(fminf(px1, tx1) - fmaxf(px0, tx0), 0.f);
    float h  = fmaxf(fminf(py1, ty1) - fmaxf(py0, ty0), 0.f);
    float inter = w * h;
    float uni   = pa + ta - inter;
    float iou   = inter / uni;            // correctly-rounded IEEE div
    float ew = fmaxf(fmaxf(px1, tx1) - fminf(px0, tx0), 0.f);
    float eh = fmaxf(fmaxf(py1, ty1) - fminf(py0, ty0), 0.f);
    float ea = ew * eh;
    return iou - (ea - uni) / ea;         // correctly-rounded IEEE div
}

__global__ __launch_bounds__(256, 4) void matcher_scan_kernel(
    const float* __restrict__ pred,       // [B,N,4] cxcywh
    const float* __restrict__ tgt,        // [B,T,4] cxcywh
    float* __restrict__ pbest,            // [NSPLIT][B*T]
    float* __restrict__ psec,             // [NSPLIT][B*T]
    int*   __restrict__ pidx)             // [NSPLIT][B*T]
{
    __shared__ float4 sp[NPB];            // pred xyxy
    __shared__ float  spa[NPB];           // pred area
    __shared__ float  sbv[4 * TT], ssv[4 * TT];
    __shared__ int    siv[4 * TT];

    const int ns  = blockIdx.x % NSPLIT;
    const int b   = blockIdx.x / NSPLIT;
    const int tid = threadIdx.x;
    const int l   = tid & 63;
    const int ng  = tid >> 6;

    if (tid < NPB) {
        const float4 pb = ((const float4*)pred)[b * NN + ns * NPB + tid];
        float4 q;
        q.x = pb.x - 0.5f * pb.z;
        q.y = pb.y - 0.5f * pb.w;
        q.z = pb.x + 0.5f * pb.z;
        q.w = pb.y + 0.5f * pb.w;
        sp[tid]  = q;
        spa[tid] = (q.z - q.x) * (q.w - q.y);
    }

    // ---- 5 target boxes per lane (lanes 0..59 active) ----
    float tx0[TPL], ty0[TPL], tx1[TPL], ty1[TPL], ta[TPL];
    #pragma unroll
    for (int j = 0; j < TPL; ++j) {
        tx0[j] = ty0[j] = tx1[j] = ty1[j] = ta[j] = 0.f;
        if (l < ALANES) {
            const float4 tb = ((const float4*)tgt)[b * TT + j * ALANES + l];
            tx0[j] = tb.x - 0.5f * tb.z;
            ty0[j] = tb.y - 0.5f * tb.w;
            tx1[j] = tb.x + 0.5f * tb.z;
            ty1[j] = tb.y + 0.5f * tb.w;
            ta[j]  = (tx1[j] - tx0[j]) * (ty1[j] - ty0[j]);
        }
    }
    __syncthreads();

    float best[TPL], sec[TPL];
    int   bl[TPL];
    #pragma unroll
    for (int j = 0; j < TPL; ++j) { best[j] = -INFINITY; sec[j] = -INFINITY; bl[j] = 0; }

    const int k0 = ng * NPW;
    #pragma unroll 5
    for (int k = 0; k < NPW; ++k) {
        const float4 p = sp[k0 + k];      // wave-uniform -> LDS broadcast
        const float pa = spa[k0 + k];
        #pragma unroll
        for (int j = 0; j < TPL; ++j) {
            const float w   = fmaxf(fminf(p.z, tx1[j]) - fmaxf(p.x, tx0[j]), 0.f);
            const float h   = fmaxf(fminf(p.w, ty1[j]) - fmaxf(p.y, ty0[j]), 0.f);
            const float inter = w * h;
            const float uni   = pa + ta[j] - inter;
            const float ew  = fmaxf(p.z, tx1[j]) - fminf(p.x, tx0[j]);  // >= 0
            const float eh  = fmaxf(p.w, ty1[j]) - fminf(p.y, ty0[j]);  // >= 0
            const float ea  = ew * eh;
            const float den = uni * ea;
            // g = inter/uni - (ea-uni)/ea = (inter*ea + uni*(uni-ea))/den
            const float num = fmaf(inter, ea, fmaf(uni, uni, -den));
            const float g   = num * __builtin_amdgcn_rcpf(den);

            sec[j] = __builtin_amdgcn_fmed3f(g, best[j], sec[j]);  // new 2nd
            if (g > best[j]) bl[j] = k;
            best[j] = fmaxf(best[j], g);
        }
    }

    if (l < ALANES) {
        #pragma unroll
        for (int j = 0; j < TPL; ++j) {
            const int u = j * ALANES + l;
            sbv[ng * TT + u] = best[j];
            ssv[ng * TT + u] = sec[j];
            siv[ng * TT + u] = k0 + bl[j];   // block-local pred index
        }
    }
    __syncthreads();

    // ---- distributed cross-wave reduce (ascending wave = ascending n) ----
    for (int u = tid; u < TT; u += 256) {
        float bb = -INFINITY, ss = -INFINITY;
        int   bi = 0;
        #pragma unroll
        for (int s = 0; s < 4; ++s) {
            const float ob = sbv[s * TT + u];
            const float os = ssv[s * TT + u];
            const int   oi = siv[s * TT + u];
            ss = fmaxf(fminf(bb, ob), fmaxf(ss, os));
            if (ob > bb) { bb = ob; bi = oi; }
        }
        const int bt = b * TT + u;
        pbest[ns * BB * TT + bt] = bb;
        psec [ns * BB * TT + bt] = ss;
        pidx [ns * BB * TT + bt] = ns * NPB + bi;   // global pred index
    }
}

__global__ __launch_bounds__(256) void matcher_finish_kernel(
    const float* __restrict__ pbest,
    const float* __restrict__ psec,
    const int*   __restrict__ pidx,
    const float* __restrict__ pred,
    const float* __restrict__ tgt,
    const unsigned char* __restrict__ mask,
    float* __restrict__ out)
{
    __shared__ int sflag[256];
    __shared__ int scount;

    const int tid = threadIdx.x;
    const int bt  = blockIdx.x * 256 + tid;   // grid covers exactly B*T
    if (tid == 0) scount = 0;
    __syncthreads();

    float best = -INFINITY, second = -INFINITY;
    int   bidx = 0;
    #pragma unroll
    for (int s = 0; s < NSPLIT; ++s) {        // ascending ns = ascending n
        const float ob = pbest[s * BB * TT + bt];
        const float os = psec [s * BB * TT + bt];
        const int   oi = pidx [s * BB * TT + bt];
        second = fmaxf(fminf(best, ob), fmaxf(second, os));
        if (ob > best) { best = ob; bidx = oi; }
    }

    if (best - second > MARGIN) {
        // approx argmax provably exact; recompute winner's GIoU bit-exactly
        const int b = bt / TT;
        const float4 pb = ((const float4*)pred)[b * NN + bidx];
        const float4 tb = ((const float4*)tgt)[bt];
        const float g = giou_exact(pb, tb);
        const bool valid = (mask[bt] != 0) && (g >= 0.5f);
        out[bt]               = (float)bidx;
        out[BB * TT + bt]     = valid ? 1.f : 0.f;
        out[2 * BB * TT + bt] = g;
    } else {
        const int pos = atomicAdd(&scount, 1);
        sflag[pos] = tid;
    }
    __syncthreads();

    // cooperative exact rescan of ambiguous targets: one wave per entry
    const int cnt  = scount;
    const int lane = tid & 63;
    const int ng   = tid >> 6;
    for (int f = ng; f < cnt; f += 4) {
        const int fbt = blockIdx.x * 256 + sflag[f];
        const int b   = fbt / TT;
        const float4 tb = ((const float4*)tgt)[fbt];

        float bestx = -INFINITY;
        int   bix   = NN;
        for (int n = lane; n < NN; n += 64) {   // ascending n per lane
            const float4 pb = ((const float4*)pred)[b * NN + n];
            const float g = giou_exact(pb, tb);
            if (g > bestx) { bestx = g; bix = n; }
        }
        // cross-lane reduce: max g, lowest n on bit-ties (numpy first-occ.)
        for (int off = 32; off >= 1; off >>= 1) {
            const float ob = __shfl_xor(bestx, off);
            const int   oi = __shfl_xor(bix, off);
            if (ob > bestx || (ob == bestx && oi < bix)) { bestx = ob; bix = oi; }
        }
        if (lane == 0) {
            const bool valid = (mask[fbt] != 0) && (bestx >= 0.5f);
            out[fbt]               = (float)bix;
            out[BB * TT + fbt]     = valid ? 1.f : 0.f;
            out[2 * BB * TT + fbt] = bestx;
        }
    }
}

extern "C" void kernel_launch(void* const* d_in, const int* in_sizes, int n_in,
                              void* d_out, int out_size, void* d_ws, size_t ws_size,
                              hipStream_t stream) {
    const float* pred = (const float*)d_in[0];
    const float* tgt  = (const float*)d_in[1];
    const unsigned char* mask = (const unsigned char*)d_in[2];
    float* out = (float*)d_out;

    const size_t seg = (size_t)NSPLIT * BB * TT * 4;   // 1.38 MB per array
    char* ws = (char*)d_ws;
    float* pbest = (float*)ws;
    float* psec  = (float*)(ws + seg);
    int*   pidx  = (int*)  (ws + 2 * seg);             // total ~4.15 MB

    matcher_scan_kernel<<<dim3(BB * NSPLIT), dim3(256), 0, stream>>>(
        pred, tgt, pbest, psec, pidx);
    matcher_finish_kernel<<<dim3(BB * TT / 256), dim3(256), 0, stream>>>(
        pbest, psec, pidx, pred, tgt, mask, out);
}